// Round 1
// baseline (472.673 us; speedup 1.0000x reference)
//
#include <hip/hip_runtime.h>
#include <math.h>

#define L_ 2
#define BAT_ 32
#define A_ 64
#define B_ 1024
#define D_ 128
#define NBITS_ 1024
#define NW 32                 // u32 words per code (1024 bits)
#define NQROWS (L_*BAT_*A_)   // 4096
#define NDROWS (L_*BAT_*B_)   // 65536
#define NROWS (NQROWS + NDROWS) // 69632

#define TM 64
#define TN 64

// ---------------- Stage 1: LSH sign-hash (fp32 GEMM + bit pack) -------------
// grid: (NROWS/TM, NBITS/TN), block 256. Each block: 64 rows x 64 bits, K=128.
__global__ __launch_bounds__(256) void hash_kernel(
    const float* __restrict__ qe, const float* __restrict__ de,
    const float* __restrict__ r, unsigned int* __restrict__ codes)
{
    __shared__ float As[TM][D_ + 4];           // +4 pad: break 128-float bank alias
    __shared__ float Bs[TN][D_ + 4];
    __shared__ unsigned int words[TM][TN / 32]; // 64 x 2 packed sign words

    const int mblk = blockIdx.x;
    const int nblk = blockIdx.y;
    const int t = threadIdx.x;

    const int row0 = mblk * TM;   // NQROWS=4096 is a multiple of TM: no straddle
    const int bit0 = nblk * TN;

    const float* abase = (row0 < NQROWS) ? (qe + (size_t)row0 * D_)
                                         : (de + (size_t)(row0 - NQROWS) * D_);
    const float* bbase = r + (size_t)bit0 * D_;

    // stage A tile: 64x128 floats, coalesced float4
    #pragma unroll
    for (int i = 0; i < 8; ++i) {
        int f = (t + i * 256) * 4;      // flat float index 0..8188
        int rr = f >> 7;                // /128
        int cc = f & 127;
        float4 v = *(const float4*)(abase + rr * D_ + cc);
        *(float4*)(&As[rr][cc]) = v;
    }
    // stage B tile (r rows bit0..bit0+63)
    #pragma unroll
    for (int i = 0; i < 8; ++i) {
        int f = (t + i * 256) * 4;
        int rr = f >> 7;
        int cc = f & 127;
        float4 v = *(const float4*)(bbase + rr * D_ + cc);
        *(float4*)(&Bs[rr][cc]) = v;
    }
    if (t < TM * (TN / 32)) ((unsigned int*)words)[t] = 0u;
    __syncthreads();

    const int tm = t >> 4;   // 0..15 -> rows tm*4..tm*4+3
    const int tn = t & 15;   // 0..15 -> bits tn*4..tn*4+3
    float acc[4][4];
    #pragma unroll
    for (int i = 0; i < 4; ++i)
        #pragma unroll
        for (int j = 0; j < 4; ++j) acc[i][j] = 0.f;

    #pragma unroll 4
    for (int k = 0; k < D_; k += 4) {
        float4 a4[4], b4[4];
        #pragma unroll
        for (int i = 0; i < 4; ++i) a4[i] = *(const float4*)(&As[tm * 4 + i][k]);
        #pragma unroll
        for (int j = 0; j < 4; ++j) b4[j] = *(const float4*)(&Bs[tn * 4 + j][k]);
        #pragma unroll
        for (int i = 0; i < 4; ++i)
            #pragma unroll
            for (int j = 0; j < 4; ++j) {
                acc[i][j] += a4[i].x * b4[j].x + a4[i].y * b4[j].y
                           + a4[i].z * b4[j].z + a4[i].w * b4[j].w;
            }
    }

    // sign-pack: bit k of a row = (dot > 0)
    #pragma unroll
    for (int i = 0; i < 4; ++i) {
        unsigned int m8 = 0;
        #pragma unroll
        for (int j = 0; j < 4; ++j)
            if (acc[i][j] > 0.f) m8 |= (1u << j);
        atomicOr(&words[tm * 4 + i][tn >> 3], m8 << ((tn * 4) & 31));
    }
    __syncthreads();

    if (t < TM * 2) {
        int rr = t >> 1, wi = t & 1;
        codes[(size_t)(row0 + rr) * NW + (nblk * 2 + wi)] = words[rr][wi];
    }
}

// ---------------- Stage 2: Hamming -> cos LUT -> mask -> out ----------------
// grid: L*BAT*(B/256) = 256 blocks, block 256. Thread owns one doc column.
__global__ __launch_bounds__(256) void simmat_kernel(
    const unsigned int* __restrict__ codes,
    const int* __restrict__ qtok, const int* __restrict__ dtok,
    float* __restrict__ out)
{
    __shared__ unsigned int qc[A_][NW];   // 8 KB query codes for this (l,b)
    __shared__ float lut[NBITS_ + 1];     // cos(pi/1024 * h), h exact integer
    __shared__ float qm[A_];

    const int blk = blockIdx.x;
    const int ct = blk & 3;
    const int b  = (blk >> 2) & 31;
    const int l  = blk >> 7;
    const int t  = threadIdx.x;

    for (int h = t; h <= NBITS_; h += 256)
        lut[h] = cosf((float)M_PI / (float)NBITS_ * (float)h);

    const unsigned int* qbase = codes + (size_t)((l * BAT_ + b) * A_) * NW;
    for (int i = t; i < A_ * NW; i += 256) qc[i / NW][i % NW] = qbase[i];
    if (t < A_) qm[t] = (qtok[b * A_ + t] != 0) ? 1.f : 0.f;
    __syncthreads();

    const int c = ct * 256 + t;
    const unsigned int* dbase =
        codes + (size_t)(NQROWS + (l * BAT_ + b) * B_ + c) * NW;
    unsigned int dc[NW];
    #pragma unroll
    for (int w = 0; w < NW; ++w) dc[w] = dbase[w];
    const float dm = (dtok[b * B_ + c] != 0) ? 1.f : 0.f;

    float* obase = out + (size_t)((b * L_ + l) * A_) * B_ + c;
    for (int a = 0; a < A_; ++a) {
        int ham = 0;
        #pragma unroll
        for (int w = 0; w < NW; ++w) ham += __popc(qc[a][w] ^ dc[w]);
        obase[(size_t)a * B_] = lut[ham] * qm[a] * dm;
    }
}

extern "C" void kernel_launch(void* const* d_in, const int* in_sizes, int n_in,
                              void* d_out, int out_size, void* d_ws, size_t ws_size,
                              hipStream_t stream) {
    const float* qe  = (const float*)d_in[0];  // [L,BAT,A,D]
    const float* de  = (const float*)d_in[1];  // [L,BAT,B,D]
    const int* qtok  = (const int*)d_in[2];    // [BAT,A]
    const int* dtok  = (const int*)d_in[3];    // [BAT,B]
    const float* r   = (const float*)d_in[4];  // [NBITS,D]
    float* out = (float*)d_out;                // [BAT,L,A,B] fp32
    unsigned int* codes = (unsigned int*)d_ws; // 69632 x 32 u32 = 8.9 MB

    dim3 g1(NROWS / TM, NBITS_ / TN);
    hash_kernel<<<g1, 256, 0, stream>>>(qe, de, r, codes);
    simmat_kernel<<<L_ * BAT_ * (B_ / 256), 256, 0, stream>>>(codes, qtok, dtok, out);
}

// Round 3
// 411.964 us; speedup vs baseline: 1.1474x; 1.1474x over previous
//
#include <hip/hip_runtime.h>
#include <math.h>

#define L_ 2
#define BAT_ 32
#define A_ 64
#define B_ 1024
#define D_ 128
#define NBITS_ 1024
#define NW 32                 // u32 words per code (1024 bits)
#define NQROWS (L_*BAT_*A_)   // 4096
#define NDROWS (L_*BAT_*B_)   // 65536
#define NROWS (NQROWS + NDROWS) // 69632

#define TM 128                // rows per block
#define TN 128                // bits per block
#define KH 64                 // K staged in halves
#define BRS (KH + 4)          // 68: ≡4 (mod 32) for bank spread, ≡0 (mod 4) for b128 align

// ---------------- Stage 1: LSH sign-hash (fp32 GEMM + bit pack) -------------
// grid: (NROWS/TM, NBITS/TN) = (544, 8), block 256.
// 128x128 tile, 8x8 micro-tile/thread with STRIDED row ownership:
//   thread (tm,tn) owns A rows {tm+16i}, B rows (bits) {tn+16j}.
// Fragment read banks: (tn+16j)*68 ≡ 4*tn (mod 32) → 8 start banks x2,
// b128 groups of 4 banks → 2 words/bank = 2-way = free (m136).
__global__ __launch_bounds__(256) void hash_kernel(
    const float* __restrict__ qe, const float* __restrict__ de,
    const float* __restrict__ r, unsigned int* __restrict__ codes)
{
    __shared__ float As[TM * BRS];              // 34816 B
    __shared__ float Bs[TN * BRS];              // 34816 B
    __shared__ unsigned int words[TM][TN / 32]; // 2048 B  (total 71680 B -> 2 blk/CU)

    const int t = threadIdx.x;
    const int row0 = blockIdx.x * TM;   // NQROWS=4096 is a multiple of 128: no straddle
    const int bit0 = blockIdx.y * TN;

    const float* abase = (row0 < NQROWS) ? (qe + (size_t)row0 * D_)
                                         : (de + (size_t)(row0 - NQROWS) * D_);
    const float* bbase = r + (size_t)bit0 * D_;

    // zero the sign-pack staging words once (visible after first __syncthreads)
    for (int i = t; i < TM * (TN / 32); i += 256)
        ((unsigned int*)words)[i] = 0u;

    const int tm = t >> 4;   // 0..15 -> A rows tm, tm+16, ..., tm+112
    const int tn = t & 15;   // 0..15 -> bits  tn, tn+16, ..., tn+112
    int arow[8], brow[8];
    #pragma unroll
    for (int i = 0; i < 8; ++i) arow[i] = (tm + 16 * i) * BRS;
    #pragma unroll
    for (int j = 0; j < 8; ++j) brow[j] = (tn + 16 * j) * BRS;

    float acc[8][8];
    #pragma unroll
    for (int i = 0; i < 8; ++i)
        #pragma unroll
        for (int j = 0; j < 8; ++j) acc[i][j] = 0.f;

    #pragma unroll
    for (int ks = 0; ks < D_; ks += KH) {
        if (ks) __syncthreads();   // protect LDS reuse between halves
        // stage 128x64 A-half and B-half; 2048 float4 each, 8 per thread
        #pragma unroll
        for (int i = 0; i < 8; ++i) {
            int f = (t + i * 256) * 4;  // flat float idx in 128x64 tile
            int rr = f >> 6;
            int cc = f & 63;
            float4 v = *(const float4*)(abase + (size_t)rr * D_ + ks + cc);
            *(float4*)(&As[rr * BRS + cc]) = v;
        }
        #pragma unroll
        for (int i = 0; i < 8; ++i) {
            int f = (t + i * 256) * 4;
            int rr = f >> 6;
            int cc = f & 63;
            float4 v = *(const float4*)(bbase + (size_t)rr * D_ + ks + cc);
            *(float4*)(&Bs[rr * BRS + cc]) = v;
        }
        __syncthreads();

        #pragma unroll 2
        for (int k = 0; k < KH; k += 4) {
            float4 b4[8];
            #pragma unroll
            for (int j = 0; j < 8; ++j)
                b4[j] = *(const float4*)(&Bs[brow[j] + k]);
            #pragma unroll
            for (int i = 0; i < 8; ++i) {
                float4 a4 = *(const float4*)(&As[arow[i] + k]);
                #pragma unroll
                for (int j = 0; j < 8; ++j)
                    acc[i][j] += a4.x * b4[j].x + a4.y * b4[j].y
                               + a4.z * b4[j].z + a4.w * b4[j].w;
            }
        }
    }

    // sign-pack: acc[i][j] is (row tm+16i, bit tn+16j).
    // Bit tn+16j -> word j>>1, position tn (j even) / tn+16 (j odd).
    #pragma unroll
    for (int i = 0; i < 8; ++i) {
        int row = tm + 16 * i;
        #pragma unroll
        for (int w = 0; w < 4; ++w) {
            unsigned int m = 0;
            if (acc[i][2 * w]     > 0.f) m |= (1u << tn);
            if (acc[i][2 * w + 1] > 0.f) m |= (1u << (tn + 16));
            atomicOr(&words[row][w], m);
        }
    }
    __syncthreads();

    for (int i = t; i < TM * 4; i += 256) {
        int rr = i >> 2, wi = i & 3;
        codes[(size_t)(row0 + rr) * NW + (blockIdx.y * 4 + wi)] = words[rr][wi];
    }
}

// ---------------- Stage 2: Hamming -> cos LUT -> mask -> out ----------------
// grid: L*BAT*8 = 512 blocks, block 256. 128 docs/block; t>>7 picks a-subrange.
__global__ __launch_bounds__(256) void simmat_kernel(
    const unsigned int* __restrict__ codes,
    const int* __restrict__ qtok, const int* __restrict__ dtok,
    float* __restrict__ out)
{
    __shared__ unsigned int qc[A_][NW];   // 8 KB query codes for this (l,b)
    __shared__ float lut[NBITS_ + 1];     // cos(pi/1024 * h), h exact integer
    __shared__ float qm[A_];

    const int blk = blockIdx.x;
    const int ct = blk & 7;
    const int b  = (blk >> 3) & 31;
    const int l  = blk >> 8;
    const int t  = threadIdx.x;

    for (int h = t; h <= NBITS_; h += 256)
        lut[h] = cosf((float)M_PI / (float)NBITS_ * (float)h);

    const unsigned int* qbase = codes + (size_t)((l * BAT_ + b) * A_) * NW;
    for (int i = t; i < A_ * NW; i += 256) qc[i / NW][i % NW] = qbase[i];
    if (t < A_) qm[t] = (qtok[b * A_ + t] != 0) ? 1.f : 0.f;
    __syncthreads();

    const int c    = ct * 128 + (t & 127);
    const int asub = (t >> 7) * 32;

    const unsigned int* dbase =
        codes + (size_t)(NQROWS + (l * BAT_ + b) * B_ + c) * NW;
    uint4 dc[8];
    #pragma unroll
    for (int w = 0; w < 8; ++w) dc[w] = *(const uint4*)(dbase + w * 4);
    const float dm = (dtok[b * B_ + c] != 0) ? 1.f : 0.f;

    float* obase = out + (size_t)((b * L_ + l) * A_) * B_ + c;
    for (int a = asub; a < asub + 32; ++a) {
        int ham = 0;
        #pragma unroll
        for (int w = 0; w < 8; ++w) {
            uint4 qv = *(const uint4*)(&qc[a][w * 4]);
            ham += __popc(qv.x ^ dc[w].x) + __popc(qv.y ^ dc[w].y)
                 + __popc(qv.z ^ dc[w].z) + __popc(qv.w ^ dc[w].w);
        }
        obase[(size_t)a * B_] = lut[ham] * qm[a] * dm;
    }
}

extern "C" void kernel_launch(void* const* d_in, const int* in_sizes, int n_in,
                              void* d_out, int out_size, void* d_ws, size_t ws_size,
                              hipStream_t stream) {
    const float* qe  = (const float*)d_in[0];  // [L,BAT,A,D]
    const float* de  = (const float*)d_in[1];  // [L,BAT,B,D]
    const int* qtok  = (const int*)d_in[2];    // [BAT,A]
    const int* dtok  = (const int*)d_in[3];    // [BAT,B]
    const float* r   = (const float*)d_in[4];  // [NBITS,D]
    float* out = (float*)d_out;                // [BAT,L,A,B] fp32
    unsigned int* codes = (unsigned int*)d_ws; // 69632 x 32 u32 = 8.9 MB

    dim3 g1(NROWS / TM, NBITS_ / TN);
    hash_kernel<<<g1, 256, 0, stream>>>(qe, de, r, codes);
    simmat_kernel<<<L_ * BAT_ * 8, 256, 0, stream>>>(codes, qtok, dtok, out);
}

// Round 4
// 383.331 us; speedup vs baseline: 1.2331x; 1.0747x over previous
//
#include <hip/hip_runtime.h>
#include <math.h>

#define L_ 2
#define BAT_ 32
#define A_ 64
#define B_ 1024
#define D_ 128
#define NBITS_ 1024
#define NW 32                 // u32 words per code (1024 bits)
#define NQROWS (L_*BAT_*A_)   // 4096
#define NDROWS (L_*BAT_*B_)   // 65536
#define NROWS (NQROWS + NDROWS) // 69632

#define TM 128                // rows per block
#define TN 128                // bits per block
#define KH 32                 // K staged in quarters -> LDS 38 KB -> 4 blocks/CU
#define BRS (KH + 4)          // 36: ≡4 (mod 32) bank spread, ≡0 (mod 4) b128 align

// ---------------- Stage 1: LSH sign-hash (fp32 GEMM + bit pack) -------------
// grid: (NROWS/TM, NBITS/TN) = (544, 8), block 256.
// 128x128 tile, 8x8 micro-tile/thread, STRIDED ownership (rows {tm+16i},
// bits {tn+16j}): fragment banks = 4*tn (mod 32), 2-way = free (m136).
// K in quarters of 32 for occupancy (4 blocks/CU = 16 waves).
__global__ __launch_bounds__(256) void hash_kernel(
    const float* __restrict__ qe, const float* __restrict__ de,
    const float* __restrict__ r, unsigned int* __restrict__ codes)
{
    __shared__ float As[TM * BRS];              // 18432 B
    __shared__ float Bs[TN * BRS];              // 18432 B
    __shared__ unsigned int words[TM][TN / 32]; // 2048 B  (total 38912 B)

    const int t = threadIdx.x;
    const int row0 = blockIdx.x * TM;   // NQROWS=4096 multiple of 128: no straddle
    const int bit0 = blockIdx.y * TN;

    const float* abase = (row0 < NQROWS) ? (qe + (size_t)row0 * D_)
                                         : (de + (size_t)(row0 - NQROWS) * D_);
    const float* bbase = r + (size_t)bit0 * D_;

    for (int i = t; i < TM * (TN / 32); i += 256)
        ((unsigned int*)words)[i] = 0u;

    const int tm = t >> 4;   // 0..15 -> A rows tm+16i
    const int tn = t & 15;   // 0..15 -> bits  tn+16j
    int arow[8], brow[8];
    #pragma unroll
    for (int i = 0; i < 8; ++i) arow[i] = (tm + 16 * i) * BRS;
    #pragma unroll
    for (int j = 0; j < 8; ++j) brow[j] = (tn + 16 * j) * BRS;

    float acc[8][8];
    #pragma unroll
    for (int i = 0; i < 8; ++i)
        #pragma unroll
        for (int j = 0; j < 8; ++j) acc[i][j] = 0.f;

    #pragma unroll
    for (int ks = 0; ks < D_; ks += KH) {
        if (ks) __syncthreads();   // protect LDS reuse between quarters
        // stage 128x32 A-slice and B-slice; 1024 float4 each, 4 per thread
        #pragma unroll
        for (int i = 0; i < 4; ++i) {
            int f = (t + i * 256) * 4;  // flat float idx in 128x32 tile
            int rr = f >> 5;
            int cc = f & 31;
            float4 v = *(const float4*)(abase + (size_t)rr * D_ + ks + cc);
            *(float4*)(&As[rr * BRS + cc]) = v;
        }
        #pragma unroll
        for (int i = 0; i < 4; ++i) {
            int f = (t + i * 256) * 4;
            int rr = f >> 5;
            int cc = f & 31;
            float4 v = *(const float4*)(bbase + (size_t)rr * D_ + ks + cc);
            *(float4*)(&Bs[rr * BRS + cc]) = v;
        }
        __syncthreads();

        #pragma unroll 2
        for (int k = 0; k < KH; k += 4) {
            float4 b4[8];
            #pragma unroll
            for (int j = 0; j < 8; ++j)
                b4[j] = *(const float4*)(&Bs[brow[j] + k]);
            #pragma unroll
            for (int i = 0; i < 8; ++i) {
                float4 a4 = *(const float4*)(&As[arow[i] + k]);
                #pragma unroll
                for (int j = 0; j < 8; ++j) {
                    // explicit fma chain: exactly 4 v_fma_f32 per 4 MACs
                    float s = acc[i][j];
                    s = __builtin_fmaf(a4.x, b4[j].x, s);
                    s = __builtin_fmaf(a4.y, b4[j].y, s);
                    s = __builtin_fmaf(a4.z, b4[j].z, s);
                    s = __builtin_fmaf(a4.w, b4[j].w, s);
                    acc[i][j] = s;
                }
            }
        }
    }

    // sign-pack: acc[i][j] is (row tm+16i, bit tn+16j).
    // Bit tn+16j -> word j>>1, position tn (j even) / tn+16 (j odd).
    #pragma unroll
    for (int i = 0; i < 8; ++i) {
        int row = tm + 16 * i;
        #pragma unroll
        for (int w = 0; w < 4; ++w) {
            unsigned int m = 0;
            if (acc[i][2 * w]     > 0.f) m |= (1u << tn);
            if (acc[i][2 * w + 1] > 0.f) m |= (1u << (tn + 16));
            atomicOr(&words[row][w], m);
        }
    }
    __syncthreads();

    for (int i = t; i < TM * 4; i += 256) {
        int rr = i >> 2, wi = i & 3;
        codes[(size_t)(row0 + rr) * NW + (blockIdx.y * 4 + wi)] = words[rr][wi];
    }
}

// ---------------- Stage 2: Hamming -> cos LUT -> mask -> out ----------------
// grid: 2048 blocks (l, b, 4 doc-chunks, 8 a-chunks), block 256 = 1 doc each.
// ~5 KB LDS, tiny VGPR -> 8 blocks/CU, full wave occupancy (was 2/CU, latency-bound).
__global__ __launch_bounds__(256) void simmat_kernel(
    const unsigned int* __restrict__ codes,
    const int* __restrict__ qtok, const int* __restrict__ dtok,
    float* __restrict__ out)
{
    __shared__ uint4 qc[8][8];            // 8 query codes (1 KB)
    __shared__ float lut[NBITS_ + 1];     // cos(pi/1024 * h), h exact integer
    __shared__ float qm[8];

    const int blk  = blockIdx.x;
    const int ct   = blk & 3;
    const int asub = (blk >> 2) & 7;
    const int b    = (blk >> 5) & 31;
    const int l    = blk >> 10;
    const int t    = threadIdx.x;

    for (int h = t; h <= NBITS_; h += 256)
        lut[h] = cosf((float)M_PI / (float)NBITS_ * (float)h);

    const int a0 = asub * 8;
    const unsigned int* qbase =
        codes + (size_t)((l * BAT_ + b) * A_ + a0) * NW;
    if (t < 8 * NW) ((unsigned int*)qc)[t] = qbase[t];
    if (t < 8) qm[t] = (qtok[b * A_ + a0 + t] != 0) ? 1.f : 0.f;
    __syncthreads();

    const int c = ct * 256 + t;
    const unsigned int* dbase =
        codes + (size_t)(NQROWS + (l * BAT_ + b) * B_ + c) * NW;
    uint4 dc[8];
    #pragma unroll
    for (int w = 0; w < 8; ++w) dc[w] = *(const uint4*)(dbase + w * 4);
    const float dm = (dtok[b * B_ + c] != 0) ? 1.f : 0.f;

    float* obase = out + ((size_t)((b * L_ + l) * A_ + a0)) * B_ + c;
    #pragma unroll
    for (int ai = 0; ai < 8; ++ai) {
        int ham = 0;
        #pragma unroll
        for (int w = 0; w < 8; ++w) {
            uint4 qv = qc[ai][w];
            ham += __popc(qv.x ^ dc[w].x) + __popc(qv.y ^ dc[w].y)
                 + __popc(qv.z ^ dc[w].z) + __popc(qv.w ^ dc[w].w);
        }
        obase[(size_t)ai * B_] = lut[ham] * qm[ai] * dm;
    }
}

extern "C" void kernel_launch(void* const* d_in, const int* in_sizes, int n_in,
                              void* d_out, int out_size, void* d_ws, size_t ws_size,
                              hipStream_t stream) {
    const float* qe  = (const float*)d_in[0];  // [L,BAT,A,D]
    const float* de  = (const float*)d_in[1];  // [L,BAT,B,D]
    const int* qtok  = (const int*)d_in[2];    // [BAT,A]
    const int* dtok  = (const int*)d_in[3];    // [BAT,B]
    const float* r   = (const float*)d_in[4];  // [NBITS,D]
    float* out = (float*)d_out;                // [BAT,L,A,B] fp32
    unsigned int* codes = (unsigned int*)d_ws; // 69632 x 32 u32 = 8.9 MB

    dim3 g1(NROWS / TM, NBITS_ / TN);
    hash_kernel<<<g1, 256, 0, stream>>>(qe, de, r, codes);
    simmat_kernel<<<L_ * BAT_ * 4 * 8, 256, 0, stream>>>(codes, qtok, dtok, out);
}

// Round 5
// 177.456 us; speedup vs baseline: 2.6636x; 2.1601x over previous
//
#include <hip/hip_runtime.h>
#include <math.h>

#define L_ 2
#define BAT_ 32
#define A_ 64
#define B_ 1024
#define D_ 128
#define NBITS_ 1024
#define NW 32                 // u32 words per code (1024 bits)
#define NQROWS (L_*BAT_*A_)   // 4096
#define NDROWS (L_*BAT_*B_)   // 65536
#define NROWS (NQROWS + NDROWS) // 69632

#define TM 128                // rows per block
#define TN 128                // bits per block
#define KH 64                 // K staged in halves
// LDS row: [hi 0..63 | lo 64..127 | pad 8] bf16 -> stride 136 elts = 272 B
// 272 B ≡ 4 dwords (mod 32 banks): b128 frag reads land 8 dwords/bank (perfectly
// balanced); %8==0 keeps 16-B alignment for ds_read_b128.
#define RS 136

typedef __bf16 bf16x4 __attribute__((ext_vector_type(4)));
typedef __bf16 bf16x8 __attribute__((ext_vector_type(8)));
typedef float  f32x4  __attribute__((ext_vector_type(4)));

// ---------------- Stage 1: LSH sign-hash (bf16-split MFMA + ballot pack) ----
// grid (NROWS/TM=544, NBITS/TN=8), block 256 = 4 waves (2x2 of 64x64 wave tiles).
// 3 MFMA passes: hi*hi + hi*lo + lo*hi recovers fp32-grade signs.
__global__ __launch_bounds__(256) void hash_kernel(
    const float* __restrict__ qe, const float* __restrict__ de,
    const float* __restrict__ r, unsigned int* __restrict__ codes)
{
    __shared__ __align__(16) __bf16 As[TM * RS];   // 34816 B
    __shared__ __align__(16) __bf16 Bs[TN * RS];   // 34816 B  (69632 total -> 2 blk/CU)

    const int t = threadIdx.x;
    const int row0 = blockIdx.x * TM;   // 4096 % 128 == 0: no q/d straddle
    const int bit0 = blockIdx.y * TN;

    const float* abase = (row0 < NQROWS) ? (qe + (size_t)row0 * D_)
                                         : (de + (size_t)(row0 - NQROWS) * D_);
    const float* bbase = r + (size_t)bit0 * D_;

    const int wv   = t >> 6;          // wave 0..3
    const int lane = t & 63;
    const int quad = lane >> 4;       // 0..3
    const int col  = lane & 15;       // 0..15
    const int wrow = (wv >> 1) * 64;  // wave's row offset in block tile
    const int wbit = (wv & 1) * 64;   // wave's bit offset in block tile

    f32x4 acc[4][4];
    #pragma unroll
    for (int ti = 0; ti < 4; ++ti)
        #pragma unroll
        for (int tj = 0; tj < 4; ++tj)
            acc[ti][tj] = (f32x4){0.f, 0.f, 0.f, 0.f};

    #pragma unroll
    for (int ks = 0; ks < D_; ks += KH) {
        if (ks) __syncthreads();
        // stage 128x64 fp32 slice of A and B, split into bf16 hi|lo in LDS
        #pragma unroll
        for (int i = 0; i < 8; ++i) {
            int f = (t + i * 256) * 4;      // flat idx in 128x64 tile
            int rr = f >> 6, cc = f & 63;
            float4 v = *(const float4*)(abase + (size_t)rr * D_ + ks + cc);
            bf16x4 hi, lo;
            hi[0] = (__bf16)v.x; hi[1] = (__bf16)v.y;
            hi[2] = (__bf16)v.z; hi[3] = (__bf16)v.w;
            lo[0] = (__bf16)(v.x - (float)hi[0]);
            lo[1] = (__bf16)(v.y - (float)hi[1]);
            lo[2] = (__bf16)(v.z - (float)hi[2]);
            lo[3] = (__bf16)(v.w - (float)hi[3]);
            *(bf16x4*)(&As[rr * RS + cc])      = hi;
            *(bf16x4*)(&As[rr * RS + 64 + cc]) = lo;
        }
        #pragma unroll
        for (int i = 0; i < 8; ++i) {
            int f = (t + i * 256) * 4;
            int rr = f >> 6, cc = f & 63;
            float4 v = *(const float4*)(bbase + (size_t)rr * D_ + ks + cc);
            bf16x4 hi, lo;
            hi[0] = (__bf16)v.x; hi[1] = (__bf16)v.y;
            hi[2] = (__bf16)v.z; hi[3] = (__bf16)v.w;
            lo[0] = (__bf16)(v.x - (float)hi[0]);
            lo[1] = (__bf16)(v.y - (float)hi[1]);
            lo[2] = (__bf16)(v.z - (float)hi[2]);
            lo[3] = (__bf16)(v.w - (float)hi[3]);
            *(bf16x4*)(&Bs[rr * RS + cc])      = hi;
            *(bf16x4*)(&Bs[rr * RS + 64 + cc]) = lo;
        }
        __syncthreads();

        // 3 segments: (A-off, B-off) = (hi,hi), (hi,lo), (lo,hi)
        #pragma unroll
        for (int seg = 0; seg < 3; ++seg) {
            const int ao = (seg == 2) ? 64 : 0;
            const int bo = (seg == 1) ? 64 : 0;
            #pragma unroll
            for (int kk = 0; kk < KH; kk += 32) {
                bf16x8 af[4], bfr[4];
                #pragma unroll
                for (int ti = 0; ti < 4; ++ti)
                    af[ti] = *(const bf16x8*)(
                        &As[(wrow + ti * 16 + col) * RS + ao + kk + quad * 8]);
                #pragma unroll
                for (int tj = 0; tj < 4; ++tj)
                    bfr[tj] = *(const bf16x8*)(
                        &Bs[(wbit + tj * 16 + col) * RS + bo + kk + quad * 8]);
                #pragma unroll
                for (int ti = 0; ti < 4; ++ti)
                    #pragma unroll
                    for (int tj = 0; tj < 4; ++tj)
                        acc[ti][tj] = __builtin_amdgcn_mfma_f32_16x16x32_bf16(
                            af[ti], bfr[tj], acc[ti][tj], 0, 0, 0);
            }
        }
    }

    // Sign-pack via ballot. C/D layout (m89): col=lane&15, row=quad*4+reg.
    // For (ti, reg): ballot over tj gives, per quad q, 16 code bits of row
    // wrow+16ti+4q+reg at bit positions tj*16+col. Lanes col<2 store one
    // 32-bit word each (w = col): words tj={2w,2w+1}.
    #pragma unroll
    for (int ti = 0; ti < 4; ++ti) {
        #pragma unroll
        for (int rg = 0; rg < 4; ++rg) {
            unsigned long long b[4];
            #pragma unroll
            for (int tj = 0; tj < 4; ++tj)
                b[tj] = __ballot(acc[ti][tj][rg] > 0.f);
            if (col < 2) {
                const int w = col;
                unsigned int lo16 = (unsigned int)(b[2 * w]     >> (16 * quad)) & 0xFFFFu;
                unsigned int hi16 = (unsigned int)(b[2 * w + 1] >> (16 * quad)) & 0xFFFFu;
                const int row = row0 + wrow + ti * 16 + quad * 4 + rg;
                codes[(size_t)row * NW + (blockIdx.y * 4 + (wv & 1) * 2 + w)] =
                    lo16 | (hi16 << 16);
            }
        }
    }
}

// ---------------- Stage 2: Hamming -> cos LUT -> mask -> out ----------------
// grid: 2048 blocks (l, b, 4 doc-chunks, 8 a-chunks), block 256 = 1 doc each.
__global__ __launch_bounds__(256) void simmat_kernel(
    const unsigned int* __restrict__ codes,
    const int* __restrict__ qtok, const int* __restrict__ dtok,
    float* __restrict__ out)
{
    __shared__ uint4 qc[8][8];            // 8 query codes (1 KB)
    __shared__ float lut[NBITS_ + 1];     // cos(pi/1024 * h), h exact integer
    __shared__ float qm[8];

    const int blk  = blockIdx.x;
    const int ct   = blk & 3;
    const int asub = (blk >> 2) & 7;
    const int b    = (blk >> 5) & 31;
    const int l    = blk >> 10;
    const int t    = threadIdx.x;

    for (int h = t; h <= NBITS_; h += 256)
        lut[h] = cosf((float)M_PI / (float)NBITS_ * (float)h);

    const int a0 = asub * 8;
    const unsigned int* qbase =
        codes + (size_t)((l * BAT_ + b) * A_ + a0) * NW;
    if (t < 8 * NW) ((unsigned int*)qc)[t] = qbase[t];
    if (t < 8) qm[t] = (qtok[b * A_ + a0 + t] != 0) ? 1.f : 0.f;
    __syncthreads();

    const int c = ct * 256 + t;
    const unsigned int* dbase =
        codes + (size_t)(NQROWS + (l * BAT_ + b) * B_ + c) * NW;
    uint4 dc[8];
    #pragma unroll
    for (int w = 0; w < 8; ++w) dc[w] = *(const uint4*)(dbase + w * 4);
    const float dm = (dtok[b * B_ + c] != 0) ? 1.f : 0.f;

    float* obase = out + ((size_t)((b * L_ + l) * A_ + a0)) * B_ + c;
    #pragma unroll
    for (int ai = 0; ai < 8; ++ai) {
        int ham = 0;
        #pragma unroll
        for (int w = 0; w < 8; ++w) {
            uint4 qv = qc[ai][w];
            ham += __popc(qv.x ^ dc[w].x) + __popc(qv.y ^ dc[w].y)
                 + __popc(qv.z ^ dc[w].z) + __popc(qv.w ^ dc[w].w);
        }
        obase[(size_t)ai * B_] = lut[ham] * qm[ai] * dm;
    }
}

extern "C" void kernel_launch(void* const* d_in, const int* in_sizes, int n_in,
                              void* d_out, int out_size, void* d_ws, size_t ws_size,
                              hipStream_t stream) {
    const float* qe  = (const float*)d_in[0];  // [L,BAT,A,D]
    const float* de  = (const float*)d_in[1];  // [L,BAT,B,D]
    const int* qtok  = (const int*)d_in[2];    // [BAT,A]
    const int* dtok  = (const int*)d_in[3];    // [BAT,B]
    const float* r   = (const float*)d_in[4];  // [NBITS,D]
    float* out = (float*)d_out;                // [BAT,L,A,B] fp32
    unsigned int* codes = (unsigned int*)d_ws; // 69632 x 32 u32 = 8.9 MB

    dim3 g1(NROWS / TM, NBITS_ / TN);
    hash_kernel<<<g1, 256, 0, stream>>>(qe, de, r, codes);
    simmat_kernel<<<L_ * BAT_ * 4 * 8, 256, 0, stream>>>(codes, qtok, dtok, out);
}